// Round 4
// baseline (407.918 us; speedup 1.0000x reference)
//
#include <hip/hip_runtime.h>
#include <hip/hip_bf16.h>

#define NN 40000
#define NE 640000
#define D  128
#define NBLK_SCAN ((NN + 255) / 256)   // 157

static __device__ inline unsigned short f2bf(float f) {
    __hip_bfloat16 h = __float2bfloat16(f);
    return *reinterpret_cast<unsigned short*>(&h);
}
static __device__ inline float bf_lo(unsigned int u) {
    unsigned int v = u << 16; return *reinterpret_cast<float*>(&v);
}
static __device__ inline float bf_hi(unsigned int u) {
    unsigned int v = u & 0xffff0000u; return *reinterpret_cast<float*>(&v);
}

// ---------------- CSR build ----------------
__global__ __launch_bounds__(256) void hist_kernel(
    const int* __restrict__ dst, int* __restrict__ counts)
{
    int e = blockIdx.x * 256 + threadIdx.x;
    if (e < NE) atomicAdd(&counts[dst[e]], 1);
}

__global__ __launch_bounds__(256) void blocksum_kernel(
    const int* __restrict__ counts, int* __restrict__ bsums)
{
    int i = blockIdx.x * 256 + threadIdx.x;
    int v = (i < NN) ? counts[i] : 0;
    #pragma unroll
    for (int off = 32; off > 0; off >>= 1) v += __shfl_down(v, off, 64);
    __shared__ int s[4];
    if ((threadIdx.x & 63) == 0) s[threadIdx.x >> 6] = v;
    __syncthreads();
    if (threadIdx.x == 0) bsums[blockIdx.x] = s[0] + s[1] + s[2] + s[3];
}

__global__ __launch_bounds__(256) void scan_bsums_kernel(
    const int* __restrict__ bsums, int* __restrict__ boffs, int* __restrict__ row_ptr)
{
    __shared__ int buf[256];
    int tid = threadIdx.x;
    int v = (tid < NBLK_SCAN) ? bsums[tid] : 0;
    buf[tid] = v;
    __syncthreads();
    for (int off = 1; off < 256; off <<= 1) {
        int t = (tid >= off) ? buf[tid - off] : 0;
        __syncthreads();
        buf[tid] += t;
        __syncthreads();
    }
    if (tid < NBLK_SCAN) boffs[tid] = buf[tid] - v;
    if (tid == 0) row_ptr[0] = 0;
}

__global__ __launch_bounds__(256) void blockscan_kernel(
    const int* __restrict__ counts, const int* __restrict__ boffs,
    int* __restrict__ row_ptr, int* __restrict__ cursor)
{
    __shared__ int buf[256];
    int tid = threadIdx.x;
    int i = blockIdx.x * 256 + tid;
    int v = (i < NN) ? counts[i] : 0;
    buf[tid] = v;
    __syncthreads();
    for (int off = 1; off < 256; off <<= 1) {
        int t = (tid >= off) ? buf[tid - off] : 0;
        __syncthreads();
        buf[tid] += t;
        __syncthreads();
    }
    int inc = buf[tid] + boffs[blockIdx.x];
    if (i < NN) { row_ptr[i + 1] = inc; cursor[i] = inc - v; }
}

__global__ __launch_bounds__(256) void fill_kernel(
    const int* __restrict__ src, const int* __restrict__ dst,
    int* __restrict__ cursor, int* __restrict__ src_sorted)
{
    int e = blockIdx.x * 256 + threadIdx.x;
    if (e >= NE) return;
    int d = dst[e];
    int pos = atomicAdd(&cursor[d], 1);
    src_sorted[pos] = src[e];
}

// ---------------- convert f32 row-table to packed bf16 ----------------
__global__ __launch_bounds__(256) void convert_bf_kernel(
    const float* __restrict__ in, unsigned int* __restrict__ out4)
{
    int i = blockIdx.x * 256 + threadIdx.x;           // 8 floats each
    const float4* in4 = reinterpret_cast<const float4*>(in);
    float4 a = in4[i * 2], b = in4[i * 2 + 1];
    uint4 u;
    u.x = f2bf(a.x) | (f2bf(a.y) << 16);
    u.y = f2bf(a.z) | (f2bf(a.w) << 16);
    u.z = f2bf(b.x) | (f2bf(b.y) << 16);
    u.w = f2bf(b.z) | (f2bf(b.w) << 16);
    reinterpret_cast<uint4*>(out4)[i] = u;
}

// ------- gather (bf16 rows): agg[n] = sum_e h_bf[src_e], f32 accumulate -----
__global__ __launch_bounds__(256) void gather_bf(
    const unsigned int* __restrict__ hbf,
    const int* __restrict__ row_ptr, const int* __restrict__ srcs,
    float* __restrict__ agg)
{
    int node = blockIdx.x * 16 + (threadIdx.x >> 4);
    int lane = threadIdx.x & 15;
    if (node >= NN) return;
    int beg = row_ptr[node], end = row_ptr[node + 1];
    float acc[8];
    #pragma unroll
    for (int j = 0; j < 8; j++) acc[j] = 0.f;
    const uint4* h4 = reinterpret_cast<const uint4*>(hbf);
    int e = beg;
    for (; e + 1 < end; e += 2) {
        int s0 = srcs[e], s1 = srcs[e + 1];
        uint4 u0 = h4[(size_t)s0 * 16 + lane];
        uint4 u1 = h4[(size_t)s1 * 16 + lane];
        acc[0] += bf_lo(u0.x); acc[1] += bf_hi(u0.x);
        acc[2] += bf_lo(u0.y); acc[3] += bf_hi(u0.y);
        acc[4] += bf_lo(u0.z); acc[5] += bf_hi(u0.z);
        acc[6] += bf_lo(u0.w); acc[7] += bf_hi(u0.w);
        acc[0] += bf_lo(u1.x); acc[1] += bf_hi(u1.x);
        acc[2] += bf_lo(u1.y); acc[3] += bf_hi(u1.y);
        acc[4] += bf_lo(u1.z); acc[5] += bf_hi(u1.z);
        acc[6] += bf_lo(u1.w); acc[7] += bf_hi(u1.w);
    }
    if (e < end) {
        uint4 u0 = h4[(size_t)srcs[e] * 16 + lane];
        acc[0] += bf_lo(u0.x); acc[1] += bf_hi(u0.x);
        acc[2] += bf_lo(u0.y); acc[3] += bf_hi(u0.y);
        acc[4] += bf_lo(u0.z); acc[5] += bf_hi(u0.z);
        acc[6] += bf_lo(u0.w); acc[7] += bf_hi(u0.w);
    }
    float4* o = reinterpret_cast<float4*>(&agg[(size_t)node * D + lane * 8]);
    o[0] = make_float4(acc[0], acc[1], acc[2], acc[3]);
    o[1] = make_float4(acc[4], acc[5], acc[6], acc[7]);
}

// ------- gather (f32 rows) — fallback when ws too small ----------------------
__global__ __launch_bounds__(256) void gather_agg(
    const float* __restrict__ h, const int* __restrict__ row_ptr,
    const int* __restrict__ srcs, float* __restrict__ agg)
{
    int node = blockIdx.x * 8 + (threadIdx.x >> 5);
    int lane = threadIdx.x & 31;
    if (node >= NN) return;
    int beg = row_ptr[node], end = row_ptr[node + 1];
    float4 acc = make_float4(0.f, 0.f, 0.f, 0.f);
    for (int e = beg; e < end; e++) {
        int s = srcs[e];
        float4 v = reinterpret_cast<const float4*>(h)[(size_t)s * 32 + lane];
        acc.x += v.x; acc.y += v.y; acc.z += v.z; acc.w += v.w;
    }
    reinterpret_cast<float4*>(agg)[(size_t)node * 32 + lane] = acc;
}

// ------ fused conv GEMM: out = act([A|H] @ [Wr;Wo] + b), M x 128, K=256 -----
// 128 threads, BM=64, BN=128, BK=32. 8x8 microtile (cols split cg*4 / cg*4+64).
// A-tile transposed in LDS so both operand reads are ds_read_b128, bank-clean.
template<bool RELU, bool WRITE_BF>
__global__ __launch_bounds__(128) void conv_gemm2(
    const float* __restrict__ A,    // agg [M][128]
    const float* __restrict__ H,    // h   [M][128]
    const float* __restrict__ Wr,   // [128][128]
    const float* __restrict__ Wo,   // [128][128]
    const float* __restrict__ bias, // [128]
    float* __restrict__ out,
    unsigned int* __restrict__ out_bf)
{
    __shared__ float CsT[32][66];   // [k][row], pad 66: staging writes 2-way max
    __shared__ float Ws[32][128];   // [k][col]

    const int tid  = threadIdx.x;
    const int row0 = blockIdx.x * 64;
    const int rg   = tid >> 4;      // 0..7  -> rows rg*8 .. rg*8+7
    const int cg   = tid & 15;      // cols cg*4..+3  and  cg*4+64..+3

    float acc[8][8];
    #pragma unroll
    for (int i = 0; i < 8; i++)
        #pragma unroll
        for (int j = 0; j < 8; j++) acc[i][j] = 0.f;

    for (int k0 = 0; k0 < 256; k0 += 32) {
        const float* S  = (k0 < 128) ? A  : H;
        const float* WW = (k0 < 128) ? Wr : Wo;
        const int kb = k0 & 127;

        // stage C^T: 64 rows x 32 ks -> 512 float4, 4 per thread (transpose)
        #pragma unroll
        for (int l = 0; l < 4; l++) {
            int lin = tid + l * 128;
            int r   = lin >> 3;          // 0..63
            int kq  = (lin & 7) * 4;     // 0..28
            float4 v = *reinterpret_cast<const float4*>(&S[(size_t)(row0 + r) * D + kb + kq]);
            CsT[kq + 0][r] = v.x;
            CsT[kq + 1][r] = v.y;
            CsT[kq + 2][r] = v.z;
            CsT[kq + 3][r] = v.w;
        }
        // stage W: 32 ks x 128 cols -> 1024 float4, 8 per thread
        #pragma unroll
        for (int l = 0; l < 8; l++) {
            int lin = tid + l * 128;
            int kk  = lin >> 5;          // 0..31
            int c4  = (lin & 31) * 4;    // 0..124
            *reinterpret_cast<float4*>(&Ws[kk][c4]) =
                *reinterpret_cast<const float4*>(&WW[(size_t)(kb + kk) * D + c4]);
        }
        __syncthreads();

        #pragma unroll 8
        for (int kk = 0; kk < 32; kk++) {
            float4 a0 = *reinterpret_cast<const float4*>(&CsT[kk][rg * 8]);
            float4 a1 = *reinterpret_cast<const float4*>(&CsT[kk][rg * 8 + 4]);
            float4 w0 = *reinterpret_cast<const float4*>(&Ws[kk][cg * 4]);
            float4 w1 = *reinterpret_cast<const float4*>(&Ws[kk][cg * 4 + 64]);
            float a[8] = {a0.x, a0.y, a0.z, a0.w, a1.x, a1.y, a1.z, a1.w};
            float w[8] = {w0.x, w0.y, w0.z, w0.w, w1.x, w1.y, w1.z, w1.w};
            #pragma unroll
            for (int i = 0; i < 8; i++)
                #pragma unroll
                for (int j = 0; j < 8; j++)
                    acc[i][j] += a[i] * w[j];
        }
        __syncthreads();
    }

    // epilogue
    float bia[8];
    #pragma unroll
    for (int j = 0; j < 4; j++) { bia[j] = bias[cg * 4 + j]; bia[j + 4] = bias[cg * 4 + 64 + j]; }

    #pragma unroll
    for (int i = 0; i < 8; i++) {
        int r = row0 + rg * 8 + i;
        float o[8];
        #pragma unroll
        for (int j = 0; j < 8; j++) {
            float v = acc[i][j] + bia[j];
            if (RELU) v = fmaxf(v, 0.f);
            o[j] = v;
        }
        *reinterpret_cast<float4*>(&out[(size_t)r * D + cg * 4]) =
            make_float4(o[0], o[1], o[2], o[3]);
        *reinterpret_cast<float4*>(&out[(size_t)r * D + cg * 4 + 64]) =
            make_float4(o[4], o[5], o[6], o[7]);
        if (WRITE_BF) {
            uint2 u0, u1;
            u0.x = f2bf(o[0]) | (f2bf(o[1]) << 16);
            u0.y = f2bf(o[2]) | (f2bf(o[3]) << 16);
            u1.x = f2bf(o[4]) | (f2bf(o[5]) << 16);
            u1.y = f2bf(o[6]) | (f2bf(o[7]) << 16);
            *reinterpret_cast<uint2*>(&out_bf[(size_t)r * 64 + cg * 2])      = u0;
            *reinterpret_cast<uint2*>(&out_bf[(size_t)r * 64 + 32 + cg * 2]) = u1;
        }
    }
}

// ---------------- fc0: out[NN][64] = relu(h[NN][128] @ W[128][64] + b) ------
__global__ __launch_bounds__(256) void fc0_kernel(
    const float* __restrict__ h, const float* __restrict__ W,
    const float* __restrict__ bias, float* __restrict__ out)
{
    __shared__ float Ws[128][64];
    __shared__ float Hs[16][128];
    const int tid = threadIdx.x;
    const float4* W4 = reinterpret_cast<const float4*>(W);
    float4* Ws4 = reinterpret_cast<float4*>(&Ws[0][0]);
    #pragma unroll
    for (int l = 0; l < 8; l++) Ws4[tid + l * 256] = W4[tid + l * 256];
    const int row0 = blockIdx.x * 16;
    const float4* h4 = reinterpret_cast<const float4*>(h + (size_t)row0 * 128);
    float4* Hs4 = reinterpret_cast<float4*>(&Hs[0][0]);
    #pragma unroll
    for (int l = 0; l < 2; l++) Hs4[tid + l * 256] = h4[tid + l * 256];
    __syncthreads();

    const int wv  = tid >> 6;
    const int col = tid & 63;
    float acc[4] = {bias[col], bias[col], bias[col], bias[col]};
    #pragma unroll 4
    for (int k = 0; k < 128; k++) {
        float w = Ws[k][col];
        #pragma unroll
        for (int j = 0; j < 4; j++) acc[j] += Hs[wv * 4 + j][k] * w;
    }
    #pragma unroll
    for (int j = 0; j < 4; j++)
        out[(size_t)(row0 + wv * 4 + j) * 64 + col] = fmaxf(acc[j], 0.f);
}

// ---------------- fc1: out[NN] = h[NN][64] @ W[64] + b ----------------------
__global__ __launch_bounds__(256) void fc1_kernel(
    const float* __restrict__ h, const float* __restrict__ W,
    const float* __restrict__ bias, float* __restrict__ out)
{
    int row  = blockIdx.x * 4 + (threadIdx.x >> 6);
    int lane = threadIdx.x & 63;
    float v = h[(size_t)row * 64 + lane] * W[lane];
    #pragma unroll
    for (int off = 32; off > 0; off >>= 1) v += __shfl_down(v, off, 64);
    if (lane == 0) out[row] = v + bias[0];
}

extern "C" void kernel_launch(void* const* d_in, const int* in_sizes, int n_in,
                              void* d_out, int out_size, void* d_ws, size_t ws_size,
                              hipStream_t stream)
{
    const float* x    = (const float*)d_in[0];
    const int*   ei   = (const int*)d_in[1];
    const int*   src  = ei;
    const int*   dst  = ei + NE;
    const float* Wrel[3]  = {(const float*)d_in[2], (const float*)d_in[5], (const float*)d_in[8]};
    const float* Wroot[3] = {(const float*)d_in[3], (const float*)d_in[6], (const float*)d_in[9]};
    const float* bb[3]    = {(const float*)d_in[4], (const float*)d_in[7], (const float*)d_in[10]};
    const float* Wfc0 = (const float*)d_in[11];
    const float* bfc0 = (const float*)d_in[12];
    const float* Wfc1 = (const float*)d_in[13];
    const float* bfc1 = (const float*)d_in[14];
    float* out = (float*)d_out;

    // ---- workspace layout ----
    float* P0 = (float*)d_ws;                          // agg scratch [NN*D] f32
    float* P1 = P0 + (size_t)NN * D;
    float* P2 = P1 + (size_t)NN * D;
    int*   row_ptr    = (int*)(P2 + (size_t)NN * D);
    int*   cursor     = row_ptr + (NN + 1);
    int*   counts     = cursor + NN;
    int*   bsums      = counts + NN;                   // [256]
    int*   boffs      = bsums + 256;                   // [256]
    int*   src_sorted = boffs + 256;                   // [NE]
    unsigned int* BF0 = (unsigned int*)(src_sorted + NE);   // [NN*64] packed bf16
    unsigned int* BF1 = BF0 + (size_t)NN * 64;
    const size_t needed = (size_t)((char*)(BF1 + (size_t)NN * 64) - (char*)d_ws);
    const bool use_bf = (ws_size >= needed);

    dim3 egrid((NE + 255) / 256);      // 2500
    dim3 ggrid(NN / 64);               // 625

    // ---- CSR build ----
    hipMemsetAsync(counts, 0, NN * sizeof(int), stream);
    hist_kernel<<<egrid, 256, 0, stream>>>(dst, counts);
    blocksum_kernel<<<dim3(NBLK_SCAN), 256, 0, stream>>>(counts, bsums);
    scan_bsums_kernel<<<dim3(1), 256, 0, stream>>>(bsums, boffs, row_ptr);
    blockscan_kernel<<<dim3(NBLK_SCAN), 256, 0, stream>>>(counts, boffs, row_ptr, cursor);
    fill_kernel<<<egrid, 256, 0, stream>>>(src, dst, cursor, src_sorted);

    if (use_bf) {
        convert_bf_kernel<<<dim3(NN * D / 8 / 256), 256, 0, stream>>>(x, BF0);
        gather_bf<<<dim3(NN / 16), 256, 0, stream>>>(BF0, row_ptr, src_sorted, P0);
        conv_gemm2<true, true><<<ggrid, 128, 0, stream>>>(P0, x, Wrel[0], Wroot[0], bb[0], P1, BF1);
        gather_bf<<<dim3(NN / 16), 256, 0, stream>>>(BF1, row_ptr, src_sorted, P0);
        conv_gemm2<true, true><<<ggrid, 128, 0, stream>>>(P0, P1, Wrel[1], Wroot[1], bb[1], P2, BF0);
        gather_bf<<<dim3(NN / 16), 256, 0, stream>>>(BF0, row_ptr, src_sorted, P0);
        conv_gemm2<false, false><<<ggrid, 128, 0, stream>>>(P0, P2, Wrel[2], Wroot[2], bb[2], P1, nullptr);
    } else {
        gather_agg<<<dim3(NN / 8), 256, 0, stream>>>(x, row_ptr, src_sorted, P0);
        conv_gemm2<true, false><<<ggrid, 128, 0, stream>>>(P0, x, Wrel[0], Wroot[0], bb[0], P1, nullptr);
        gather_agg<<<dim3(NN / 8), 256, 0, stream>>>(P1, row_ptr, src_sorted, P0);
        conv_gemm2<true, false><<<ggrid, 128, 0, stream>>>(P0, P1, Wrel[1], Wroot[1], bb[1], P2, nullptr);
        gather_agg<<<dim3(NN / 8), 256, 0, stream>>>(P2, row_ptr, src_sorted, P0);
        conv_gemm2<false, false><<<ggrid, 128, 0, stream>>>(P0, P2, Wrel[2], Wroot[2], bb[2], P1, nullptr);
    }

    // fc stack
    fc0_kernel<<<dim3(NN / 16), 256, 0, stream>>>(P1, Wfc0, bfc0, P2);
    fc1_kernel<<<dim3(NN / 4), 256, 0, stream>>>(P2, Wfc1, bfc1, out);
}

// Round 5
// 278.944 us; speedup vs baseline: 1.4624x; 1.4624x over previous
//
#include <hip/hip_runtime.h>
#include <hip/hip_bf16.h>

#define NN 40000
#define NE 640000
#define D  128
#define NBLK_SCAN ((NN + 255) / 256)   // 157

typedef __attribute__((ext_vector_type(8))) short bf16x8;
typedef __attribute__((ext_vector_type(4))) float f32x4;

static __device__ inline unsigned short f2bf(float f) {
    __hip_bfloat16 h = __float2bfloat16(f);
    return *reinterpret_cast<unsigned short*>(&h);
}
static __device__ inline float bfval(unsigned short h) {
    unsigned int v = ((unsigned int)h) << 16; return *reinterpret_cast<float*>(&v);
}
static __device__ inline float bf_lo(unsigned int u) {
    unsigned int v = u << 16; return *reinterpret_cast<float*>(&v);
}
static __device__ inline float bf_hi(unsigned int u) {
    unsigned int v = u & 0xffff0000u; return *reinterpret_cast<float*>(&v);
}

// ---------------- CSR build ----------------
__global__ __launch_bounds__(256) void hist_kernel(
    const int* __restrict__ dst, int* __restrict__ counts)
{
    int e = blockIdx.x * 256 + threadIdx.x;
    if (e < NE) atomicAdd(&counts[dst[e]], 1);
}

__global__ __launch_bounds__(256) void blocksum_kernel(
    const int* __restrict__ counts, int* __restrict__ bsums)
{
    int i = blockIdx.x * 256 + threadIdx.x;
    int v = (i < NN) ? counts[i] : 0;
    #pragma unroll
    for (int off = 32; off > 0; off >>= 1) v += __shfl_down(v, off, 64);
    __shared__ int s[4];
    if ((threadIdx.x & 63) == 0) s[threadIdx.x >> 6] = v;
    __syncthreads();
    if (threadIdx.x == 0) bsums[blockIdx.x] = s[0] + s[1] + s[2] + s[3];
}

__global__ __launch_bounds__(256) void scan_bsums_kernel(
    const int* __restrict__ bsums, int* __restrict__ boffs, int* __restrict__ row_ptr)
{
    __shared__ int buf[256];
    int tid = threadIdx.x;
    int v = (tid < NBLK_SCAN) ? bsums[tid] : 0;
    buf[tid] = v;
    __syncthreads();
    for (int off = 1; off < 256; off <<= 1) {
        int t = (tid >= off) ? buf[tid - off] : 0;
        __syncthreads();
        buf[tid] += t;
        __syncthreads();
    }
    if (tid < NBLK_SCAN) boffs[tid] = buf[tid] - v;
    if (tid == 0) row_ptr[0] = 0;
}

__global__ __launch_bounds__(256) void blockscan_kernel(
    const int* __restrict__ counts, const int* __restrict__ boffs,
    int* __restrict__ row_ptr, int* __restrict__ cursor)
{
    __shared__ int buf[256];
    int tid = threadIdx.x;
    int i = blockIdx.x * 256 + tid;
    int v = (i < NN) ? counts[i] : 0;
    buf[tid] = v;
    __syncthreads();
    for (int off = 1; off < 256; off <<= 1) {
        int t = (tid >= off) ? buf[tid - off] : 0;
        __syncthreads();
        buf[tid] += t;
        __syncthreads();
    }
    int inc = buf[tid] + boffs[blockIdx.x];
    if (i < NN) { row_ptr[i + 1] = inc; cursor[i] = inc - v; }
}

__global__ __launch_bounds__(256) void fill_kernel(
    const int* __restrict__ src, const int* __restrict__ dst,
    int* __restrict__ cursor, int* __restrict__ src_sorted)
{
    int e = blockIdx.x * 256 + threadIdx.x;
    if (e >= NE) return;
    int d = dst[e];
    int pos = atomicAdd(&cursor[d], 1);
    src_sorted[pos] = src[e];
}

// ---------------- convert f32 row-table to packed bf16 ----------------
__global__ __launch_bounds__(256) void convert_bf_kernel(
    const float* __restrict__ in, unsigned int* __restrict__ out4)
{
    int i = blockIdx.x * 256 + threadIdx.x;           // 8 floats each
    const float4* in4 = reinterpret_cast<const float4*>(in);
    float4 a = in4[i * 2], b = in4[i * 2 + 1];
    uint4 u;
    u.x = f2bf(a.x) | (f2bf(a.y) << 16);
    u.y = f2bf(a.z) | (f2bf(a.w) << 16);
    u.z = f2bf(b.x) | (f2bf(b.y) << 16);
    u.w = f2bf(b.z) | (f2bf(b.w) << 16);
    reinterpret_cast<uint4*>(out4)[i] = u;
}

// ------- gather (bf16 rows): agg[n] = sum_e h_bf[src_e], f32 accumulate -----
__global__ __launch_bounds__(256) void gather_bf(
    const unsigned int* __restrict__ hbf,
    const int* __restrict__ row_ptr, const int* __restrict__ srcs,
    float* __restrict__ agg)
{
    int node = blockIdx.x * 16 + (threadIdx.x >> 4);
    int lane = threadIdx.x & 15;
    if (node >= NN) return;
    int beg = row_ptr[node], end = row_ptr[node + 1];
    float acc[8];
    #pragma unroll
    for (int j = 0; j < 8; j++) acc[j] = 0.f;
    const uint4* h4 = reinterpret_cast<const uint4*>(hbf);
    int e = beg;
    for (; e + 1 < end; e += 2) {
        int s0 = srcs[e], s1 = srcs[e + 1];
        uint4 u0 = h4[(size_t)s0 * 16 + lane];
        uint4 u1 = h4[(size_t)s1 * 16 + lane];
        acc[0] += bf_lo(u0.x); acc[1] += bf_hi(u0.x);
        acc[2] += bf_lo(u0.y); acc[3] += bf_hi(u0.y);
        acc[4] += bf_lo(u0.z); acc[5] += bf_hi(u0.z);
        acc[6] += bf_lo(u0.w); acc[7] += bf_hi(u0.w);
        acc[0] += bf_lo(u1.x); acc[1] += bf_hi(u1.x);
        acc[2] += bf_lo(u1.y); acc[3] += bf_hi(u1.y);
        acc[4] += bf_lo(u1.z); acc[5] += bf_hi(u1.z);
        acc[6] += bf_lo(u1.w); acc[7] += bf_hi(u1.w);
    }
    if (e < end) {
        uint4 u0 = h4[(size_t)srcs[e] * 16 + lane];
        acc[0] += bf_lo(u0.x); acc[1] += bf_hi(u0.x);
        acc[2] += bf_lo(u0.y); acc[3] += bf_hi(u0.y);
        acc[4] += bf_lo(u0.z); acc[5] += bf_hi(u0.z);
        acc[6] += bf_lo(u0.w); acc[7] += bf_hi(u0.w);
    }
    float4* o = reinterpret_cast<float4*>(&agg[(size_t)node * D + lane * 8]);
    o[0] = make_float4(acc[0], acc[1], acc[2], acc[3]);
    o[1] = make_float4(acc[4], acc[5], acc[6], acc[7]);
}

// ------- gather (f32 rows) — fallback when ws too small ----------------------
__global__ __launch_bounds__(256) void gather_agg(
    const float* __restrict__ h, const int* __restrict__ row_ptr,
    const int* __restrict__ srcs, float* __restrict__ agg)
{
    int node = blockIdx.x * 8 + (threadIdx.x >> 5);
    int lane = threadIdx.x & 31;
    if (node >= NN) return;
    int beg = row_ptr[node], end = row_ptr[node + 1];
    float4 acc = make_float4(0.f, 0.f, 0.f, 0.f);
    for (int e = beg; e < end; e++) {
        int s = srcs[e];
        float4 v = reinterpret_cast<const float4*>(h)[(size_t)s * 32 + lane];
        acc.x += v.x; acc.y += v.y; acc.z += v.z; acc.w += v.w;
    }
    reinterpret_cast<float4*>(agg)[(size_t)node * 32 + lane] = acc;
}

// ---- W pre-pass: transpose + split [Wr;Wo] -> WT_hi/lo [128 cols][256 k] ---
__global__ __launch_bounds__(256) void wsplit_kernel(
    const float* __restrict__ Wr, const float* __restrict__ Wo,
    unsigned short* __restrict__ WTh, unsigned short* __restrict__ WTl)
{
    int c = blockIdx.x;       // 0..127 (output col)
    int k = threadIdx.x;      // 0..255 (concat K)
    const float* Wsrc = (k < 128) ? Wr : Wo;
    float w = Wsrc[(size_t)(k & 127) * D + c];
    unsigned short hi = f2bf(w);
    float lo = w - bfval(hi);
    WTh[(size_t)c * 256 + k] = hi;
    WTl[(size_t)c * 256 + k] = f2bf(lo);
}

// ---- MFMA conv GEMM: out = act([A|H] @ [Wr;Wo] + b) via split-bf16 --------
// 256 thr / 4 waves, BM=64 (16 rows per wave), 8 K-steps of 32.
// 3 MFMAs per fragment: Ah*Wh + Al*Wh + Ah*Wl  (error ~2^-18, effectively f32)
template<bool RELU, bool WRITE_BF>
__global__ __launch_bounds__(256) void conv_mfma(
    const float* __restrict__ A,     // agg [M][128] f32
    const float* __restrict__ H,     // h   [M][128] f32
    const unsigned short* __restrict__ WTh,  // [128][256] bf16 (transposed)
    const unsigned short* __restrict__ WTl,
    const float* __restrict__ bias,
    float* __restrict__ out,
    unsigned short* __restrict__ out_bf)
{
    __shared__ unsigned short AsH[64][40];    // stride 40 (80B) to de-bank
    __shared__ unsigned short AsL[64][40];
    __shared__ unsigned short WsH[128][40];
    __shared__ unsigned short WsL[128][40];

    const int tid  = threadIdx.x;
    const int row0 = blockIdx.x * 64;
    const int w    = tid >> 6;        // wave 0..3 -> rows w*16..+15
    const int l    = tid & 63;
    const int l15  = l & 15;
    const int kg   = l >> 4;          // k-group 0..3

    f32x4 acc[8];
    #pragma unroll
    for (int cf = 0; cf < 8; cf++) acc[cf] = (f32x4){0.f, 0.f, 0.f, 0.f};

    for (int s = 0; s < 8; s++) {
        const float* Sf = (s < 4) ? A : H;
        const int kb = (s & 3) * 32;

        // stage A chunk: 64 rows x 32 k, f32 -> hi/lo bf16 (coalesced 16B reads)
        #pragma unroll
        for (int t = 0; t < 2; t++) {
            int lin = tid + t * 256;            // 0..511
            int r   = lin >> 3;                 // 0..63
            int kq  = (lin & 7) * 4;            // 0..28
            float4 v = *reinterpret_cast<const float4*>(&Sf[(size_t)(row0 + r) * D + kb + kq]);
            unsigned short h0 = f2bf(v.x), h1 = f2bf(v.y), h2 = f2bf(v.z), h3 = f2bf(v.w);
            ushort4 hi, lo;
            hi.x = h0; hi.y = h1; hi.z = h2; hi.w = h3;
            lo.x = f2bf(v.x - bfval(h0));
            lo.y = f2bf(v.y - bfval(h1));
            lo.z = f2bf(v.z - bfval(h2));
            lo.w = f2bf(v.w - bfval(h3));
            *reinterpret_cast<ushort4*>(&AsH[r][kq]) = hi;
            *reinterpret_cast<ushort4*>(&AsL[r][kq]) = lo;
        }
        // stage W chunk: 128 cols x 32 k (pre-split, coalesced b128)
        #pragma unroll
        for (int t = 0; t < 2; t++) {
            int lin = tid + t * 256;            // 0..511
            int c   = lin >> 2;                 // 0..127
            int q   = lin & 3;                  // 16B quarter of the 64B col-chunk
            uint4 vh = *reinterpret_cast<const uint4*>(&WTh[(size_t)c * 256 + s * 32 + q * 8]);
            uint4 vl = *reinterpret_cast<const uint4*>(&WTl[(size_t)c * 256 + s * 32 + q * 8]);
            *reinterpret_cast<uint4*>(&WsH[c][q * 8]) = vh;
            *reinterpret_cast<uint4*>(&WsL[c][q * 8]) = vl;
        }
        __syncthreads();

        // A fragments: lane row = l&15 (+ wave slab), k = kg*8..+7
        bf16x8 ah = *reinterpret_cast<const bf16x8*>(&AsH[w * 16 + l15][kg * 8]);
        bf16x8 al = *reinterpret_cast<const bf16x8*>(&AsL[w * 16 + l15][kg * 8]);
        #pragma unroll
        for (int cf = 0; cf < 8; cf++) {
            bf16x8 wh = *reinterpret_cast<const bf16x8*>(&WsH[cf * 16 + l15][kg * 8]);
            bf16x8 wl = *reinterpret_cast<const bf16x8*>(&WsL[cf * 16 + l15][kg * 8]);
            acc[cf] = __builtin_amdgcn_mfma_f32_16x16x32_bf16(ah, wh, acc[cf], 0, 0, 0);
            acc[cf] = __builtin_amdgcn_mfma_f32_16x16x32_bf16(al, wh, acc[cf], 0, 0, 0);
            acc[cf] = __builtin_amdgcn_mfma_f32_16x16x32_bf16(ah, wl, acc[cf], 0, 0, 0);
        }
        __syncthreads();
    }

    // epilogue: C/D layout col=l&15, row=4*(l>>4)+reg
    #pragma unroll
    for (int cf = 0; cf < 8; cf++) {
        int c = cf * 16 + l15;
        float b = bias[c];
        #pragma unroll
        for (int r = 0; r < 4; r++) {
            int row = row0 + w * 16 + kg * 4 + r;
            float v = acc[cf][r] + b;
            if (RELU) v = fmaxf(v, 0.f);
            out[(size_t)row * D + c] = v;
            if (WRITE_BF) out_bf[(size_t)row * D + c] = f2bf(v);
        }
    }
}

// -------- fp32 fallback conv GEMM (ws too small for bf path) ---------------
template<bool RELU>
__global__ __launch_bounds__(128) void conv_gemm2(
    const float* __restrict__ A, const float* __restrict__ H,
    const float* __restrict__ Wr, const float* __restrict__ Wo,
    const float* __restrict__ bias, float* __restrict__ out)
{
    __shared__ float CsT[32][66];
    __shared__ float Ws[32][128];
    const int tid  = threadIdx.x;
    const int row0 = blockIdx.x * 64;
    const int rg   = tid >> 4;
    const int cg   = tid & 15;
    float acc[8][8];
    #pragma unroll
    for (int i = 0; i < 8; i++)
        #pragma unroll
        for (int j = 0; j < 8; j++) acc[i][j] = 0.f;
    for (int k0 = 0; k0 < 256; k0 += 32) {
        const float* S  = (k0 < 128) ? A  : H;
        const float* WW = (k0 < 128) ? Wr : Wo;
        const int kb = k0 & 127;
        #pragma unroll
        for (int t = 0; t < 4; t++) {
            int lin = tid + t * 128;
            int r   = lin >> 3;
            int kq  = (lin & 7) * 4;
            float4 v = *reinterpret_cast<const float4*>(&S[(size_t)(row0 + r) * D + kb + kq]);
            CsT[kq + 0][r] = v.x; CsT[kq + 1][r] = v.y;
            CsT[kq + 2][r] = v.z; CsT[kq + 3][r] = v.w;
        }
        #pragma unroll
        for (int t = 0; t < 8; t++) {
            int lin = tid + t * 128;
            int kk  = lin >> 5;
            int c4  = (lin & 31) * 4;
            *reinterpret_cast<float4*>(&Ws[kk][c4]) =
                *reinterpret_cast<const float4*>(&WW[(size_t)(kb + kk) * D + c4]);
        }
        __syncthreads();
        #pragma unroll 8
        for (int kk = 0; kk < 32; kk++) {
            float4 a0 = *reinterpret_cast<const float4*>(&CsT[kk][rg * 8]);
            float4 a1 = *reinterpret_cast<const float4*>(&CsT[kk][rg * 8 + 4]);
            float4 w0 = *reinterpret_cast<const float4*>(&Ws[kk][cg * 4]);
            float4 w1 = *reinterpret_cast<const float4*>(&Ws[kk][cg * 4 + 64]);
            float a[8] = {a0.x, a0.y, a0.z, a0.w, a1.x, a1.y, a1.z, a1.w};
            float ww[8] = {w0.x, w0.y, w0.z, w0.w, w1.x, w1.y, w1.z, w1.w};
            #pragma unroll
            for (int i = 0; i < 8; i++)
                #pragma unroll
                for (int j = 0; j < 8; j++)
                    acc[i][j] += a[i] * ww[j];
        }
        __syncthreads();
    }
    #pragma unroll
    for (int i = 0; i < 8; i++) {
        int r = row0 + rg * 8 + i;
        #pragma unroll
        for (int j = 0; j < 4; j++) {
            float v0 = acc[i][j] + bias[cg * 4 + j];
            float v1 = acc[i][j + 4] + bias[cg * 4 + 64 + j];
            if (RELU) { v0 = fmaxf(v0, 0.f); v1 = fmaxf(v1, 0.f); }
            out[(size_t)r * D + cg * 4 + j] = v0;
            out[(size_t)r * D + cg * 4 + 64 + j] = v1;
        }
    }
}

// ---------------- fc0: out[NN][64] = relu(h[NN][128] @ W[128][64] + b) ------
__global__ __launch_bounds__(256) void fc0_kernel(
    const float* __restrict__ h, const float* __restrict__ W,
    const float* __restrict__ bias, float* __restrict__ out)
{
    __shared__ float Ws[128][64];
    __shared__ float Hs[16][128];
    const int tid = threadIdx.x;
    const float4* W4 = reinterpret_cast<const float4*>(W);
    float4* Ws4 = reinterpret_cast<float4*>(&Ws[0][0]);
    #pragma unroll
    for (int l = 0; l < 8; l++) Ws4[tid + l * 256] = W4[tid + l * 256];
    const int row0 = blockIdx.x * 16;
    const float4* h4 = reinterpret_cast<const float4*>(h + (size_t)row0 * 128);
    float4* Hs4 = reinterpret_cast<float4*>(&Hs[0][0]);
    #pragma unroll
    for (int l = 0; l < 2; l++) Hs4[tid + l * 256] = h4[tid + l * 256];
    __syncthreads();

    const int wv  = tid >> 6;
    const int col = tid & 63;
    float acc[4] = {bias[col], bias[col], bias[col], bias[col]};
    #pragma unroll 4
    for (int k = 0; k < 128; k++) {
        float w = Ws[k][col];
        #pragma unroll
        for (int j = 0; j < 4; j++) acc[j] += Hs[wv * 4 + j][k] * w;
    }
    #pragma unroll
    for (int j = 0; j < 4; j++)
        out[(size_t)(row0 + wv * 4 + j) * 64 + col] = fmaxf(acc[j], 0.f);
}

// ---------------- fc1: out[NN] = h[NN][64] @ W[64] + b ----------------------
__global__ __launch_bounds__(256) void fc1_kernel(
    const float* __restrict__ h, const float* __restrict__ W,
    const float* __restrict__ bias, float* __restrict__ out)
{
    int row  = blockIdx.x * 4 + (threadIdx.x >> 6);
    int lane = threadIdx.x & 63;
    float v = h[(size_t)row * 64 + lane] * W[lane];
    #pragma unroll
    for (int off = 32; off > 0; off >>= 1) v += __shfl_down(v, off, 64);
    if (lane == 0) out[row] = v + bias[0];
}

extern "C" void kernel_launch(void* const* d_in, const int* in_sizes, int n_in,
                              void* d_out, int out_size, void* d_ws, size_t ws_size,
                              hipStream_t stream)
{
    const float* x    = (const float*)d_in[0];
    const int*   ei   = (const int*)d_in[1];
    const int*   src  = ei;
    const int*   dst  = ei + NE;
    const float* Wrel[3]  = {(const float*)d_in[2], (const float*)d_in[5], (const float*)d_in[8]};
    const float* Wroot[3] = {(const float*)d_in[3], (const float*)d_in[6], (const float*)d_in[9]};
    const float* bb[3]    = {(const float*)d_in[4], (const float*)d_in[7], (const float*)d_in[10]};
    const float* Wfc0 = (const float*)d_in[11];
    const float* bfc0 = (const float*)d_in[12];
    const float* Wfc1 = (const float*)d_in[13];
    const float* bfc1 = (const float*)d_in[14];
    float* out = (float*)d_out;

    // ---- workspace layout ----
    float* P0 = (float*)d_ws;                          // agg scratch [NN*D] f32
    float* P1 = P0 + (size_t)NN * D;
    float* P2 = P1 + (size_t)NN * D;
    int*   row_ptr    = (int*)(P2 + (size_t)NN * D);
    int*   cursor     = row_ptr + (NN + 1);
    int*   counts     = cursor + NN;
    int*   bsums      = counts + NN;                   // [256]
    int*   boffs      = bsums + 256;                   // [256]
    int*   src_sorted = boffs + 256;                   // [NE]
    unsigned int* BF0 = (unsigned int*)(src_sorted + NE);   // [NN*64] packed bf16
    unsigned int* BF1 = BF0 + (size_t)NN * 64;
    unsigned short* WT = (unsigned short*)(BF1 + (size_t)NN * 64);  // 3 layers x (hi+lo) x 128x256
    const size_t needed = (size_t)((char*)(WT + 3 * 2 * 128 * 256) - (char*)d_ws);
    const bool use_bf = (ws_size >= needed);

    dim3 egrid((NE + 255) / 256);      // 2500
    dim3 ggrid(NN / 64);               // 625

    // ---- CSR build ----
    hipMemsetAsync(counts, 0, NN * sizeof(int), stream);
    hist_kernel<<<egrid, 256, 0, stream>>>(dst, counts);
    blocksum_kernel<<<dim3(NBLK_SCAN), 256, 0, stream>>>(counts, bsums);
    scan_bsums_kernel<<<dim3(1), 256, 0, stream>>>(bsums, boffs, row_ptr);
    blockscan_kernel<<<dim3(NBLK_SCAN), 256, 0, stream>>>(counts, boffs, row_ptr, cursor);
    fill_kernel<<<egrid, 256, 0, stream>>>(src, dst, cursor, src_sorted);

    if (use_bf) {
        unsigned short* WTh[3]; unsigned short* WTl[3];
        for (int i = 0; i < 3; i++) {
            WTh[i] = WT + (size_t)i * 2 * 128 * 256;
            WTl[i] = WTh[i] + 128 * 256;
            wsplit_kernel<<<dim3(128), 256, 0, stream>>>(Wrel[i], Wroot[i], WTh[i], WTl[i]);
        }
        convert_bf_kernel<<<dim3(NN * D / 8 / 256), 256, 0, stream>>>(x, BF0);

        gather_bf<<<dim3(NN / 16), 256, 0, stream>>>(BF0, row_ptr, src_sorted, P0);
        conv_mfma<true, true><<<ggrid, 256, 0, stream>>>(P0, x, WTh[0], WTl[0], bb[0], P1, (unsigned short*)BF1);
        gather_bf<<<dim3(NN / 16), 256, 0, stream>>>(BF1, row_ptr, src_sorted, P0);
        conv_mfma<true, true><<<ggrid, 256, 0, stream>>>(P0, P1, WTh[1], WTl[1], bb[1], P2, (unsigned short*)BF0);
        gather_bf<<<dim3(NN / 16), 256, 0, stream>>>(BF0, row_ptr, src_sorted, P0);
        conv_mfma<false, false><<<ggrid, 256, 0, stream>>>(P0, P2, WTh[2], WTl[2], bb[2], P1, nullptr);
    } else {
        gather_agg<<<dim3(NN / 8), 256, 0, stream>>>(x, row_ptr, src_sorted, P0);
        conv_gemm2<true><<<ggrid, 128, 0, stream>>>(P0, x, Wrel[0], Wroot[0], bb[0], P1);
        gather_agg<<<dim3(NN / 8), 256, 0, stream>>>(P1, row_ptr, src_sorted, P0);
        conv_gemm2<true><<<ggrid, 128, 0, stream>>>(P0, P1, Wrel[1], Wroot[1], bb[1], P2);
        gather_agg<<<dim3(NN / 8), 256, 0, stream>>>(P2, row_ptr, src_sorted, P0);
        conv_gemm2<false><<<ggrid, 128, 0, stream>>>(P0, P2, Wrel[2], Wroot[2], bb[2], P1);
    }

    // fc stack
    fc0_kernel<<<dim3(NN / 16), 256, 0, stream>>>(P1, Wfc0, bfc0, P2);
    fc1_kernel<<<dim3(NN / 4), 256, 0, stream>>>(P2, Wfc1, bfc1, out);
}